// Round 5
// baseline (939.287 us; speedup 1.0000x reference)
//
#include <hip/hip_runtime.h>
#include <hip/hip_bf16.h>
#include <math.h>

// Problem constants (from reference)
#define N_NODES 100000
#define F_IN    256
#define HID     128
#define NCLS    32
#define NEDGES  1600000
#define EPS_C   0.1f
#define GAMMA_C 0.1f

// Bucketed counting sort for CSR build
#define NBK  782        // ceil(100000/128) buckets of 128 nodes
#define BCAP 3072       // per-bucket capacity (mean 2048, +22 sigma)

typedef __attribute__((ext_vector_type(8))) short short8;   // 8 bf16 = 4 VGPRs (MFMA A/B frag)
typedef __attribute__((ext_vector_type(4))) float floatx4;  // MFMA C/D frag

__device__ __forceinline__ float bf2f(unsigned short u) {
    union { unsigned int u; float f; } c;
    c.u = ((unsigned int)u) << 16;
    return c.f;
}
__device__ __forceinline__ unsigned short f2bf(float f) {
    union { float f; unsigned int u; } c; c.f = f;
    unsigned int u = c.u;
    u += 0x7FFFu + ((u >> 16) & 1u);   // round-to-nearest-even
    return (unsigned short)(u >> 16);
}

// Polymorphic scalar load: md=1 -> buffer is f32, md=0 -> bf16
__device__ __forceinline__ float ldf(const void* p, size_t i, int md) {
    return md ? ((const float*)p)[i] : bf2f(((const unsigned short*)p)[i]);
}
__device__ __forceinline__ short8 ld8(const void* p, size_t i, int md) {
    if (md) {
        const float* q = (const float*)p + i;
        short8 r;
#pragma unroll
        for (int j = 0; j < 8; ++j) r[j] = (short)f2bf(q[j]);
        return r;
    }
    return *(const short8*)((const unsigned short*)p + i);
}

// ---------------------------------------------------------------- dtype probe
__global__ void k_detect(const unsigned short* __restrict__ x, int* __restrict__ mode) {
    __shared__ int cnt;
    if (threadIdx.x == 0) cnt = 0;
    __syncthreads();
    float v = fabsf(bf2f(x[2 * threadIdx.x]));
    if (v > 1e4f || !isfinite(v)) atomicAdd(&cnt, 1);
    __syncthreads();
    if (threadIdx.x == 0) *mode = (cnt >= 8) ? 1 : 0;
}

// ---------------------------------------------------------------- CSR build v2
__global__ void k_zeroi(int* __restrict__ p, int n) {
    int i = blockIdx.x * blockDim.x + threadIdx.x;
    if (i < n) p[i] = 0;
}

// Pass 1: bin edges by dst bucket; pack (src<<7)|(dst&127) in 4B
__global__ void k_bucket(const int* __restrict__ erow, const int* __restrict__ ecol,
                         int* __restrict__ bcnt, unsigned int* __restrict__ pairs, int e) {
    int i = blockIdx.x * blockDim.x + threadIdx.x;
    if (i >= e) return;
    int dst = ecol[i], src = erow[i];
    int b = dst >> 7;
    int p = atomicAdd(&bcnt[b], 1);
    if (p < BCAP)
        pairs[(size_t)b * BCAP + p] = ((unsigned int)src << 7) | (unsigned int)(dst & 127);
}

// Pass 2: exclusive scan of 782 bucket counts (single 1024-thread block)
__global__ void k_bscan(const int* __restrict__ bcnt, int* __restrict__ bbase) {
    __shared__ int s[1024];
    int v = (threadIdx.x < NBK) ? bcnt[threadIdx.x] : 0;
    s[threadIdx.x] = v;
    __syncthreads();
#pragma unroll
    for (int off = 1; off < 1024; off <<= 1) {
        int t = (threadIdx.x >= off) ? s[threadIdx.x - off] : 0;
        __syncthreads();
        s[threadIdx.x] += t;
        __syncthreads();
    }
    if (threadIdx.x < NBK) bbase[threadIdx.x] = s[threadIdx.x] - v;
}

// Pass 3: per-bucket local counting sort in LDS -> CSR segment + deg/dinv
__global__ __launch_bounds__(256) void k_build(
    const int* __restrict__ bcnt, const int* __restrict__ bbase,
    const unsigned int* __restrict__ pairs,
    int* __restrict__ srt, int* __restrict__ row_start, int* __restrict__ cend,
    float* __restrict__ dinv, int n)
{
    __shared__ int lh[128];
    __shared__ int lo[128];
    __shared__ unsigned int se[BCAP];
    int b = blockIdx.x;
    int nb = bcnt[b]; if (nb > BCAP) nb = BCAP;
    int base = bbase[b];
    if (threadIdx.x < 128) lh[threadIdx.x] = 0;
    __syncthreads();
    for (int e = threadIdx.x; e < nb; e += 256) {
        unsigned int pk = pairs[(size_t)b * BCAP + e];
        se[e] = pk;
        atomicAdd(&lh[pk & 127u], 1);
    }
    __syncthreads();
    if (threadIdx.x < 128) lo[threadIdx.x] = lh[threadIdx.x];
    __syncthreads();
#pragma unroll
    for (int off = 1; off < 128; off <<= 1) {
        int t = (threadIdx.x < 128 && threadIdx.x >= off) ? lo[threadIdx.x - off] : 0;
        __syncthreads();
        if (threadIdx.x < 128) lo[threadIdx.x] += t;   // inclusive scan
        __syncthreads();
    }
    int node = b * 128 + threadIdx.x;
    if (threadIdx.x < 128 && node < n) {
        int inc = lo[threadIdx.x], cnt = lh[threadIdx.x];
        row_start[node] = base + inc - cnt;
        cend[node]      = base + inc;
        dinv[node]      = rsqrtf((float)cnt + 1.0f);
    }
    __syncthreads();
    if (threadIdx.x < 128) lh[threadIdx.x] = lo[threadIdx.x] - lh[threadIdx.x]; // cursor = exclusive
    __syncthreads();
    for (int e = threadIdx.x; e < nb; e += 256) {
        unsigned int pk = se[e];
        int pos = atomicAdd(&lh[pk & 127u], 1);
        srt[base + pos] = (int)(pk >> 7);
    }
}

// ---------------------------------------------------------------- weights
__global__ void k_aw(const void* __restrict__ W, unsigned short* __restrict__ aw,
                     const int* __restrict__ dmode, int d) {
    int idx = blockIdx.x * blockDim.x + threadIdx.x;
    if (idx >= d * d) return;
    int md = dmode[0];
    int n = idx / d, k = idx - n * d;
    float v = ldf(W, n * d + k, md) - ldf(W, k * d + n, md) - ((n == k) ? GAMMA_C : 0.0f);
    aw[idx] = f2bf(v);
}

// ---------------------------------------------------------------- GEMM v2
// C[M,NC] = A[M,K] @ B[NC,K]^T. B staged in padded LDS (free 2-way bank alias).
// 4 waves/block, 4 row-tiles/wave -> 256 rows/block, NT = NC/16 col tiles.
// EPI: 0 relu(acc+bias) | 2 acc+bias | 5 dinv[r]*acc (pre-scaled xw for gather)
//      3 ASC: h + EPS*tanh(acc + agg + dinv*xws + bias)          (K==NC)
//      4 ASC + fused log_softmax -> opout (poly dtype)           (K==NC==32)
template<int K, int NC, int EPI, bool APOLY, bool BPOLY>
__global__ __launch_bounds__(256) void k_gemm2(
    const void* A, const void* B, const void* bias,
    unsigned short* Cout,
    const unsigned short* agg, const unsigned short* xw, const float* dinv,
    const int* dmode, void* opout, int M)
{
    constexpr int KP = K + 8;
    constexpr int NT = NC / 16;
    constexpr int RT = 4;
    __shared__ __align__(16) unsigned short sB[NC * KP];
    const int md = dmode[0];

    for (int base = threadIdx.x * 8; base < NC * K; base += 2048) {
        int r = base / K, c = base - r * K;
        if (BPOLY && md) {
            const float* q = (const float*)B + base;
#pragma unroll
            for (int j = 0; j < 8; ++j) sB[r * KP + c + j] = f2bf(q[j]);
        } else {
            *(short8*)(sB + r * KP + c) = *(const short8*)((const unsigned short*)B + base);
        }
    }
    __syncthreads();

    const int lane = threadIdx.x & 63;
    const int wave = threadIdx.x >> 6;
    const int l15  = lane & 15;
    const int quad = lane >> 4;
    const int row0 = blockIdx.x * 256 + wave * 64;
    if (row0 >= M) return;

    int am[RT];
#pragma unroll
    for (int rt = 0; rt < RT; ++rt) {
        int r = row0 + rt * 16 + l15;
        am[rt] = r < M ? r : M - 1;
    }

    floatx4 acc[RT][NT];
#pragma unroll
    for (int rt = 0; rt < RT; ++rt)
#pragma unroll
        for (int t = 0; t < NT; ++t) acc[rt][t] = (floatx4){0.f, 0.f, 0.f, 0.f};

#pragma unroll 2
    for (int kk = 0; kk < K; kk += 32) {
        short8 a[RT];
#pragma unroll
        for (int rt = 0; rt < RT; ++rt)
            a[rt] = APOLY ? ld8(A, (size_t)am[rt] * K + kk + quad * 8, md)
                          : *(const short8*)((const unsigned short*)A + (size_t)am[rt] * K + kk + quad * 8);
        short8 b[NT];
#pragma unroll
        for (int t = 0; t < NT; ++t)
            b[t] = *(const short8*)(sB + (t * 16 + l15) * KP + kk + quad * 8);
#pragma unroll
        for (int rt = 0; rt < RT; ++rt)
#pragma unroll
            for (int t = 0; t < NT; ++t)
                acc[rt][t] = __builtin_amdgcn_mfma_f32_16x16x32_bf16(a[rt], b[t], acc[rt][t], 0, 0, 0);
    }

    const unsigned short* Ares = (const unsigned short*)A;
    // C/D layout: col = lane&15, row = quad*4 + reg  [m89-verified]
#pragma unroll
    for (int rt = 0; rt < RT; ++rt) {
#pragma unroll
        for (int reg = 0; reg < 4; ++reg) {
            int rr = row0 + rt * 16 + quad * 4 + reg;
            if (EPI == 4) {
                int rrc = rr < M ? rr : M - 1;
                float dv = dinv[rrc];
                float val[NT];
#pragma unroll
                for (int t = 0; t < NT; ++t) {
                    int col = t * 16 + l15;
                    float z = acc[rt][t][reg]
                            + bf2f(agg[(size_t)rrc * NC + col])
                            + dv * bf2f(xw[(size_t)rrc * NC + col])
                            + ldf(bias, col, md);
                    val[t] = bf2f(Ares[(size_t)rrc * K + col]) + EPS_C * tanhf(z);
                }
                float m = val[0];
#pragma unroll
                for (int t = 1; t < NT; ++t) m = fmaxf(m, val[t]);
#pragma unroll
                for (int msk = 1; msk < 16; msk <<= 1) m = fmaxf(m, __shfl_xor(m, msk));
                float s = 0.f;
#pragma unroll
                for (int t = 0; t < NT; ++t) s += expf(val[t] - m);
#pragma unroll
                for (int msk = 1; msk < 16; msk <<= 1) s += __shfl_xor(s, msk);
                float ls = m + logf(s);
                if (rr < M) {
#pragma unroll
                    for (int t = 0; t < NT; ++t) {
                        int col = t * 16 + l15;
                        float r = val[t] - ls;
                        if (md) ((float*)opout)[(size_t)rr * NC + col] = r;
                        else    ((unsigned short*)opout)[(size_t)rr * NC + col] = f2bf(r);
                    }
                }
            } else {
                if (rr >= M) continue;
#pragma unroll
                for (int t = 0; t < NT; ++t) {
                    int col = t * 16 + l15;
                    float v = acc[rt][t][reg];
                    if (EPI == 0) { v += ldf(bias, col, md); v = v > 0.f ? v : 0.f; }
                    else if (EPI == 2) { v += ldf(bias, col, md); }
                    else if (EPI == 5) { v *= dinv[rr]; }
                    else if (EPI == 3) {
                        float dv = dinv[rr];
                        float z = v + bf2f(agg[(size_t)rr * NC + col])
                                + dv * bf2f(xw[(size_t)rr * NC + col])
                                + ldf(bias, col, md);
                        v = bf2f(Ares[(size_t)rr * K + col]) + EPS_C * tanhf(z);
                    }
                    Cout[(size_t)rr * NC + col] = f2bf(v);
                }
            }
        }
    }
}

// ---------------------------------------------------------------- fused lin2+phi2
__global__ __launch_bounds__(256) void k_lin2phi2(
    const unsigned short* __restrict__ A, const void* __restrict__ B1,
    const void* __restrict__ bias, const void* __restrict__ B2,
    unsigned short* __restrict__ h3, unsigned short* __restrict__ xws2,
    const float* __restrict__ dinv, const int* __restrict__ dmode, int M)
{
    constexpr int K1 = 128, KP1 = 136, KP2 = 40;
    __shared__ __align__(16) unsigned short sB1[32 * KP1];
    __shared__ __align__(16) unsigned short sB2[32 * KP2];
    __shared__ __align__(16) unsigned short sT[256 * KP2];
    const int md = dmode[0];

    for (int base = threadIdx.x * 8; base < 32 * K1; base += 2048) {
        int r = base / K1, c = base - r * K1;
        if (md) {
            const float* q = (const float*)B1 + base;
#pragma unroll
            for (int j = 0; j < 8; ++j) sB1[r * KP1 + c + j] = f2bf(q[j]);
        } else {
            *(short8*)(sB1 + r * KP1 + c) = *(const short8*)((const unsigned short*)B1 + base);
        }
    }
    for (int base = threadIdx.x * 8; base < 32 * 32; base += 2048) {
        int r = base / 32, c = base - r * 32;
        if (md) {
            const float* q = (const float*)B2 + base;
#pragma unroll
            for (int j = 0; j < 8; ++j) sB2[r * KP2 + c + j] = f2bf(q[j]);
        } else {
            *(short8*)(sB2 + r * KP2 + c) = *(const short8*)((const unsigned short*)B2 + base);
        }
    }
    __syncthreads();

    const int lane = threadIdx.x & 63;
    const int wave = threadIdx.x >> 6;
    const int l15  = lane & 15;
    const int quad = lane >> 4;
    const int row0 = blockIdx.x * 256 + wave * 64;

    int am[4];
#pragma unroll
    for (int rt = 0; rt < 4; ++rt) {
        int r = row0 + rt * 16 + l15;
        am[rt] = r < M ? r : M - 1;
    }

    floatx4 acc[4][2];
#pragma unroll
    for (int rt = 0; rt < 4; ++rt) { acc[rt][0] = (floatx4){0,0,0,0}; acc[rt][1] = (floatx4){0,0,0,0}; }

#pragma unroll
    for (int kk = 0; kk < K1; kk += 32) {
#pragma unroll
        for (int rt = 0; rt < 4; ++rt) {
            short8 a = *(const short8*)(A + (size_t)am[rt] * K1 + kk + quad * 8);
#pragma unroll
            for (int t = 0; t < 2; ++t) {
                short8 b = *(const short8*)(sB1 + (t * 16 + l15) * KP1 + kk + quad * 8);
                acc[rt][t] = __builtin_amdgcn_mfma_f32_16x16x32_bf16(a, b, acc[rt][t], 0, 0, 0);
            }
        }
    }
#pragma unroll
    for (int rt = 0; rt < 4; ++rt)
#pragma unroll
        for (int reg = 0; reg < 4; ++reg) {
            int rr = row0 + rt * 16 + quad * 4 + reg;
            int lr = wave * 64 + rt * 16 + quad * 4 + reg;
#pragma unroll
            for (int t = 0; t < 2; ++t) {
                int col = t * 16 + l15;
                unsigned short hv = f2bf(acc[rt][t][reg] + ldf(bias, col, md));
                sT[lr * KP2 + col] = hv;
                if (rr < M) h3[(size_t)rr * 32 + col] = hv;
            }
        }
    __syncthreads();

    floatx4 a2[4][2];
#pragma unroll
    for (int rt = 0; rt < 4; ++rt) {
        short8 a = *(const short8*)(sT + (wave * 64 + rt * 16 + l15) * KP2 + quad * 8);
#pragma unroll
        for (int t = 0; t < 2; ++t) {
            short8 b = *(const short8*)(sB2 + (t * 16 + l15) * KP2 + quad * 8);
            a2[rt][t] = __builtin_amdgcn_mfma_f32_16x16x32_bf16(a, b, (floatx4){0,0,0,0}, 0, 0, 0);
        }
    }
#pragma unroll
    for (int rt = 0; rt < 4; ++rt)
#pragma unroll
        for (int reg = 0; reg < 4; ++reg) {
            int rr = row0 + rt * 16 + quad * 4 + reg;
            if (rr >= M) continue;
            float dv = dinv[rr];
#pragma unroll
            for (int t = 0; t < 2; ++t)
                xws2[(size_t)rr * 32 + t * 16 + l15] = f2bf(dv * a2[rt][t][reg]);
        }
}

// ---------------------------------------------------------------- gather
// agg[i] = dinv[i] * sum_{j in in(i)} xws[src_j]   (xws pre-scaled by dinv[src])
template<int D, int LPN>
__global__ __launch_bounds__(256) void k_gather(
    const int* __restrict__ srt, const int* __restrict__ rs,
    const int* __restrict__ cend,
    const unsigned short* __restrict__ xws, const float* __restrict__ dinv,
    unsigned short* __restrict__ agg, int n)
{
    constexpr int NPB = 256 / LPN;
    int node = blockIdx.x * NPB + threadIdx.x / LPN;
    int l = threadIdx.x % LPN;
    if (node >= n) return;
    int j = rs[node], end = cend[node];
    float a0 = 0.f, a1 = 0.f;
    for (; j + 1 < end; j += 2) {
        int s0 = srt[j], s1 = srt[j + 1];
        unsigned int p0 = *(const unsigned int*)(xws + (size_t)s0 * D + l * 2);
        unsigned int p1 = *(const unsigned int*)(xws + (size_t)s1 * D + l * 2);
        a0 += bf2f((unsigned short)(p0 & 0xFFFFu)) + bf2f((unsigned short)(p1 & 0xFFFFu));
        a1 += bf2f((unsigned short)(p0 >> 16))     + bf2f((unsigned short)(p1 >> 16));
    }
    if (j < end) {
        int s0 = srt[j];
        unsigned int p0 = *(const unsigned int*)(xws + (size_t)s0 * D + l * 2);
        a0 += bf2f((unsigned short)(p0 & 0xFFFFu));
        a1 += bf2f((unsigned short)(p0 >> 16));
    }
    float dn = dinv[node];
    unsigned int out = (unsigned int)f2bf(dn * a0) | ((unsigned int)f2bf(dn * a1) << 16);
    *(unsigned int*)(agg + (size_t)node * D + l * 2) = out;
}

// ---------------------------------------------------------------- launch
extern "C" void kernel_launch(void* const* d_in, const int* in_sizes, int n_in,
                              void* d_out, int out_size, void* d_ws, size_t ws_size,
                              hipStream_t stream)
{
    const void* x      = d_in[0];
    const void* lin1_w = d_in[1];
    const void* lin1_b = d_in[2];
    const void* lin2_w = d_in[3];
    const void* lin2_b = d_in[4];
    const void* W1     = d_in[5];
    const void* phi1w  = d_in[6];
    const void* b1     = d_in[7];
    const void* W2     = d_in[8];
    const void* phi2w  = d_in[9];
    const void* b2     = d_in[10];
    const int* eidx    = (const int*)d_in[11];
    const int* erow = eidx;
    const int* ecol = eidx + NEDGES;

    // Workspace (high-water ~85.2 MB — R1 failed at 128.5MB, keep <= ~85MB):
    char* ws = (char*)d_ws;
    float* dinv          = (float*)ws;                    // [N] f32
    int*   dmode         = (int*)(ws + 400000);
    unsigned short* aw1  = (unsigned short*)(ws + 401408);
    unsigned short* aw2  = (unsigned short*)(ws + 435200);
    int* bcnt            = (int*)(ws + 440320);           // [782]
    int* bbase           = (int*)(ws + 443648);           // [782]
    int* row_start       = (int*)(ws + 446976);           // [N]
    int* cend            = (int*)(ws + 846976);           // [N]
    int* srt             = (int*)(ws + 1246976);          // [E] 6.4MB, ends < 8388608
    unsigned short* h1   = (unsigned short*)(ws + 8388608);           // [N,128]
    unsigned short* xws1 = h1 + (size_t)N_NODES * HID;                // [N,128]
    unsigned short* agg1 = xws1 + (size_t)N_NODES * HID;              // [N,128]
    unsigned short* h2   = xws1;   // EPI3 in-place (read-before-write per thread)
    unsigned short* h3   = h1;     // h1 dead after EPI3
    unsigned short* xws2 = agg1;   // agg1 dead after EPI3
    unsigned short* agg2 = agg1 + (size_t)N_NODES * NCLS;
    // pairs aliases agg1 region (9.6MB <= 25.6MB; consumed by k_build before
    // k_gather writes agg1 — stream-ordered)
    unsigned int* pairs  = (unsigned int*)agg1;

    const int GB = 256;
    const int NBLK = (N_NODES + 255) / 256;
    k_detect<<<1, 256, 0, stream>>>((const unsigned short*)x, dmode);

    // CSR build v2: bucketed counting sort
    k_zeroi<<<(NBK + GB - 1) / GB, GB, 0, stream>>>(bcnt, NBK);
    k_bucket<<<(NEDGES + GB - 1) / GB, GB, 0, stream>>>(erow, ecol, bcnt, pairs, NEDGES);
    k_bscan<<<1, 1024, 0, stream>>>(bcnt, bbase);
    k_build<<<NBK, 256, 0, stream>>>(bcnt, bbase, pairs, srt, row_start, cend, dinv, N_NODES);

    // antisymmetric weights
    k_aw<<<(HID * HID + GB - 1) / GB, GB, 0, stream>>>(W1, aw1, dmode, HID);
    k_aw<<<(NCLS * NCLS + GB - 1) / GB, GB, 0, stream>>>(W2, aw2, dmode, NCLS);

    // h1 = relu(x @ lin1_w.T + lin1_b)
    k_gemm2<256, 128, 0, true, true><<<NBLK, 256, 0, stream>>>(
        x, lin1_w, lin1_b, h1, nullptr, nullptr, nullptr, dmode, nullptr, N_NODES);
    // xws1 = dinv * (h1 @ phi1_w.T)
    k_gemm2<128, 128, 5, false, true><<<NBLK, 256, 0, stream>>>(
        h1, phi1w, nullptr, xws1, nullptr, nullptr, dinv, dmode, nullptr, N_NODES);
    // agg1 = dinv * gather(xws1)
    k_gather<128, 64><<<(N_NODES + 3) / 4, 256, 0, stream>>>(
        srt, row_start, cend, xws1, dinv, agg1, N_NODES);
    // h2 = h1 + EPS*tanh(h1@aw1.T + agg1 + dinv*xws1 + b1)   (in-place on xws1)
    k_gemm2<128, 128, 3, false, false><<<NBLK, 256, 0, stream>>>(
        h1, aw1, b1, h2, agg1, xws1, dinv, dmode, nullptr, N_NODES);
    // h3 = h2@lin2_w.T + lin2_b ; xws2 = dinv*(h3@phi2_w.T)   (fused)
    k_lin2phi2<<<NBLK, 256, 0, stream>>>(h2, lin2_w, lin2_b, phi2w, h3, xws2, dinv, dmode, N_NODES);
    // agg2 = dinv * gather(xws2)
    k_gather<32, 16><<<(N_NODES + 15) / 16, 256, 0, stream>>>(
        srt, row_start, cend, xws2, dinv, agg2, N_NODES);
    // out = log_softmax(h3 + EPS*tanh(h3@aw2.T + agg2 + dinv*xws2 + b2))  (fused)
    k_gemm2<32, 32, 4, false, false><<<NBLK, 256, 0, stream>>>(
        h3, aw2, b2, nullptr, agg2, xws2, dinv, dmode, d_out, N_NODES);
}

// Round 6
// 610.972 us; speedup vs baseline: 1.5374x; 1.5374x over previous
//
#include <hip/hip_runtime.h>
#include <hip/hip_bf16.h>
#include <math.h>

// Problem constants (from reference)
#define N_NODES 100000
#define F_IN    256
#define HID     128
#define NCLS    32
#define NEDGES  1600000
#define EPS_C   0.1f
#define GAMMA_C 0.1f

// CSR build: radix partition into 782 buckets of 128 nodes, no global atomics
#define NBK   782                  // ceil(100000/128)
#define CHUNK 4096
#define NCH   391                  // ceil(1600000/4096)
#define BMAX  4096                 // bucket cap for k_build LDS (mean 2046, +45 sigma)

typedef __attribute__((ext_vector_type(8))) short short8;   // 8 bf16 = 4 VGPRs (MFMA A/B frag)
typedef __attribute__((ext_vector_type(4))) float floatx4;  // MFMA C/D frag

__device__ __forceinline__ float bf2f(unsigned short u) {
    union { unsigned int u; float f; } c;
    c.u = ((unsigned int)u) << 16;
    return c.f;
}
__device__ __forceinline__ unsigned short f2bf(float f) {
    union { float f; unsigned int u; } c; c.f = f;
    unsigned int u = c.u;
    u += 0x7FFFu + ((u >> 16) & 1u);   // round-to-nearest-even
    return (unsigned short)(u >> 16);
}

// Polymorphic scalar load: md=1 -> buffer is f32, md=0 -> bf16
__device__ __forceinline__ float ldf(const void* p, size_t i, int md) {
    return md ? ((const float*)p)[i] : bf2f(((const unsigned short*)p)[i]);
}
__device__ __forceinline__ short8 ld8(const void* p, size_t i, int md) {
    if (md) {
        const float* q = (const float*)p + i;
        short8 r;
#pragma unroll
        for (int j = 0; j < 8; ++j) r[j] = (short)f2bf(q[j]);
        return r;
    }
    return *(const short8*)((const unsigned short*)p + i);
}

// ---------------------------------------------------------------- dtype probe
__global__ void k_detect(const unsigned short* __restrict__ x, int* __restrict__ mode) {
    __shared__ int cnt;
    if (threadIdx.x == 0) cnt = 0;
    __syncthreads();
    float v = fabsf(bf2f(x[2 * threadIdx.x]));
    if (v > 1e4f || !isfinite(v)) atomicAdd(&cnt, 1);
    __syncthreads();
    if (threadIdx.x == 0) *mode = (cnt >= 8) ? 1 : 0;
}

// ---------------------------------------------------------------- CSR build v3
// Pass 1: per-chunk LDS histogram over 782 buckets -> hist[blk*NBK + b]
__global__ __launch_bounds__(256) void k_hist2(const int* __restrict__ ecol,
                                               int* __restrict__ hist, int e) {
    __shared__ int lh[NBK];
    for (int i = threadIdx.x; i < NBK; i += 256) lh[i] = 0;
    __syncthreads();
    int base = blockIdx.x * CHUNK;
    int lim = base + CHUNK; if (lim > e) lim = e;
    for (int i = base + threadIdx.x; i < lim; i += 256)
        atomicAdd(&lh[ecol[i] >> 7], 1);
    __syncthreads();
    for (int i = threadIdx.x; i < NBK; i += 256) hist[blockIdx.x * NBK + i] = lh[i];
}

// Pass 2a: per-bucket totals
__global__ __launch_bounds__(256) void k_tot(const int* __restrict__ hist, int* __restrict__ tot) {
    __shared__ int s[256];
    int b = blockIdx.x;
    int v = 0;
    for (int blk = threadIdx.x; blk < NCH; blk += 256) v += hist[blk * NBK + b];
    s[threadIdx.x] = v;
    __syncthreads();
#pragma unroll
    for (int off = 128; off > 0; off >>= 1) {
        if (threadIdx.x < off) s[threadIdx.x] += s[threadIdx.x + off];
        __syncthreads();
    }
    if (threadIdx.x == 0) tot[b] = s[0];
}

// Pass 2b: exclusive scan of 782 totals (single block)
__global__ void k_bscan(const int* __restrict__ tot, int* __restrict__ bbase) {
    __shared__ int s[1024];
    int v = (threadIdx.x < NBK) ? tot[threadIdx.x] : 0;
    s[threadIdx.x] = v;
    __syncthreads();
#pragma unroll
    for (int off = 1; off < 1024; off <<= 1) {
        int t = (threadIdx.x >= off) ? s[threadIdx.x - off] : 0;
        __syncthreads();
        s[threadIdx.x] += t;
        __syncthreads();
    }
    if (threadIdx.x < NBK) bbase[threadIdx.x] = s[threadIdx.x] - v;
}

// Pass 2c: per-bucket column scan over chunks -> off[blk*NBK + b]
__global__ __launch_bounds__(512) void k_colscan(const int* __restrict__ hist,
                                                 const int* __restrict__ bbase,
                                                 int* __restrict__ off) {
    __shared__ int s[512];
    int b = blockIdx.x, t = threadIdx.x;
    int v = (t < NCH) ? hist[t * NBK + b] : 0;
    s[t] = v;
    __syncthreads();
#pragma unroll
    for (int o = 1; o < 512; o <<= 1) {
        int u = (t >= o) ? s[t - o] : 0;
        __syncthreads();
        s[t] += u;
        __syncthreads();
    }
    if (t < NCH) off[t * NBK + b] = s[t] - v + bbase[b];
}

// Pass 3: block-local counting sort into LDS, ordered coalesced flush to pairs
__global__ __launch_bounds__(256) void k_pass3(
    const int* __restrict__ erow, const int* __restrict__ ecol,
    const int* __restrict__ off, unsigned int* __restrict__ pairs, int e)
{
    __shared__ int lh[NBK];
    __shared__ int lex[NBK + 1];
    __shared__ int cur[NBK];
    __shared__ int wsum[256];
    __shared__ unsigned int sp[CHUNK];
    int base = blockIdx.x * CHUNK;
    int lim = base + CHUNK; if (lim > e) lim = e;
    int cnt = lim - base;

    for (int i = threadIdx.x; i < NBK; i += 256) lh[i] = 0;
    __syncthreads();
    for (int i = base + threadIdx.x; i < lim; i += 256)
        atomicAdd(&lh[ecol[i] >> 7], 1);
    __syncthreads();

    // exclusive scan of lh (782) with 256 threads, 4 elems each
    int t4 = threadIdx.x * 4;
    int a0 = (t4 + 0 < NBK) ? lh[t4 + 0] : 0;
    int a1 = (t4 + 1 < NBK) ? lh[t4 + 1] : 0;
    int a2 = (t4 + 2 < NBK) ? lh[t4 + 2] : 0;
    int a3 = (t4 + 3 < NBK) ? lh[t4 + 3] : 0;
    int mysum = a0 + a1 + a2 + a3;
    wsum[threadIdx.x] = mysum;
    __syncthreads();
#pragma unroll
    for (int o = 1; o < 256; o <<= 1) {
        int u = (threadIdx.x >= o) ? wsum[threadIdx.x - o] : 0;
        __syncthreads();
        wsum[threadIdx.x] += u;
        __syncthreads();
    }
    int run = wsum[threadIdx.x] - mysum;
    if (t4 + 0 < NBK) { lex[t4 + 0] = run;            cur[t4 + 0] = run; }
    if (t4 + 1 < NBK) { lex[t4 + 1] = run + a0;       cur[t4 + 1] = run + a0; }
    if (t4 + 2 < NBK) { lex[t4 + 2] = run + a0 + a1;  cur[t4 + 2] = run + a0 + a1; }
    if (t4 + 3 < NBK) { lex[t4 + 3] = run + a0 + a1 + a2; cur[t4 + 3] = run + a0 + a1 + a2; }
    if (threadIdx.x == 0) lex[NBK] = cnt;
    __syncthreads();

    // place into LDS staging via LDS cursors
    for (int i = base + threadIdx.x; i < lim; i += 256) {
        int dst = ecol[i], src = erow[i];
        int b = dst >> 7;
        int p = atomicAdd(&cur[b], 1);
        sp[p] = ((unsigned int)src << 7) | (unsigned int)(dst & 127);
    }
    __syncthreads();

    // ordered flush: consecutive i in a bucket -> consecutive global addresses
    for (int i = threadIdx.x; i < cnt; i += 256) {
        int loB = 0, hiB = NBK;               // lex[loB] <= i < lex[hiB]
        while (hiB - loB > 1) {
            int mid = (loB + hiB) >> 1;
            if (lex[mid] <= i) loB = mid; else hiB = mid;
        }
        pairs[off[blockIdx.x * NBK + loB] + (i - lex[loB])] = sp[i];
    }
}

// Pass 4: per-bucket node-level counting sort in LDS -> srt + row_start/cend/dinv
__global__ __launch_bounds__(256) void k_build(
    const int* __restrict__ tot, const int* __restrict__ bbase,
    const unsigned int* __restrict__ pairs,
    int* __restrict__ srt, int* __restrict__ row_start, int* __restrict__ cend,
    float* __restrict__ dinv, int n)
{
    __shared__ int lh[128];
    __shared__ int lo[128];
    __shared__ unsigned int se[BMAX];
    int b = blockIdx.x;
    int nb = tot[b]; if (nb > BMAX) nb = BMAX;
    int base = bbase[b];
    if (threadIdx.x < 128) lh[threadIdx.x] = 0;
    __syncthreads();
    for (int e = threadIdx.x; e < nb; e += 256) {
        unsigned int pk = pairs[(size_t)base + e];
        se[e] = pk;
        atomicAdd(&lh[pk & 127u], 1);
    }
    __syncthreads();
    if (threadIdx.x < 128) lo[threadIdx.x] = lh[threadIdx.x];
    __syncthreads();
#pragma unroll
    for (int off = 1; off < 128; off <<= 1) {
        int t = (threadIdx.x < 128 && threadIdx.x >= off) ? lo[threadIdx.x - off] : 0;
        __syncthreads();
        if (threadIdx.x < 128) lo[threadIdx.x] += t;   // inclusive scan
        __syncthreads();
    }
    int node = b * 128 + threadIdx.x;
    if (threadIdx.x < 128 && node < n) {
        int inc = lo[threadIdx.x], cnt = lh[threadIdx.x];
        row_start[node] = base + inc - cnt;
        cend[node]      = base + inc;
        dinv[node]      = rsqrtf((float)cnt + 1.0f);
    }
    __syncthreads();
    if (threadIdx.x < 128) lh[threadIdx.x] = lo[threadIdx.x] - lh[threadIdx.x]; // exclusive cursor
    __syncthreads();
    for (int e = threadIdx.x; e < nb; e += 256) {
        unsigned int pk = se[e];
        int pos = atomicAdd(&lh[pk & 127u], 1);
        srt[base + pos] = (int)(pk >> 7);
    }
}

// ---------------------------------------------------------------- weights
__global__ void k_aw(const void* __restrict__ W, unsigned short* __restrict__ aw,
                     const int* __restrict__ dmode, int d) {
    int idx = blockIdx.x * blockDim.x + threadIdx.x;
    if (idx >= d * d) return;
    int md = dmode[0];
    int n = idx / d, k = idx - n * d;
    float v = ldf(W, n * d + k, md) - ldf(W, k * d + n, md) - ((n == k) ? GAMMA_C : 0.0f);
    aw[idx] = f2bf(v);
}

// ---------------------------------------------------------------- GEMM v2
// C[M,NC] = A[M,K] @ B[NC,K]^T. B staged in padded LDS (free 2-way bank alias).
// 4 waves/block, 4 row-tiles/wave -> 256 rows/block, NT = NC/16 col tiles.
// EPI: 0 relu(acc+bias) | 2 acc+bias | 5 dinv[r]*acc (pre-scaled xw for gather)
//      3 ASC: h + EPS*tanh(acc + agg + dinv*xws + bias)          (K==NC)
//      4 ASC + fused log_softmax -> opout (poly dtype)           (K==NC==32)
template<int K, int NC, int EPI, bool APOLY, bool BPOLY>
__global__ __launch_bounds__(256) void k_gemm2(
    const void* A, const void* B, const void* bias,
    unsigned short* Cout,
    const unsigned short* agg, const unsigned short* xw, const float* dinv,
    const int* dmode, void* opout, int M)
{
    constexpr int KP = K + 8;
    constexpr int NT = NC / 16;
    constexpr int RT = 4;
    __shared__ __align__(16) unsigned short sB[NC * KP];
    const int md = dmode[0];

    for (int base = threadIdx.x * 8; base < NC * K; base += 2048) {
        int r = base / K, c = base - r * K;
        if (BPOLY && md) {
            const float* q = (const float*)B + base;
#pragma unroll
            for (int j = 0; j < 8; ++j) sB[r * KP + c + j] = f2bf(q[j]);
        } else {
            *(short8*)(sB + r * KP + c) = *(const short8*)((const unsigned short*)B + base);
        }
    }
    __syncthreads();

    const int lane = threadIdx.x & 63;
    const int wave = threadIdx.x >> 6;
    const int l15  = lane & 15;
    const int quad = lane >> 4;
    const int row0 = blockIdx.x * 256 + wave * 64;
    if (row0 >= M) return;

    int am[RT];
#pragma unroll
    for (int rt = 0; rt < RT; ++rt) {
        int r = row0 + rt * 16 + l15;
        am[rt] = r < M ? r : M - 1;
    }

    floatx4 acc[RT][NT];
#pragma unroll
    for (int rt = 0; rt < RT; ++rt)
#pragma unroll
        for (int t = 0; t < NT; ++t) acc[rt][t] = (floatx4){0.f, 0.f, 0.f, 0.f};

#pragma unroll 2
    for (int kk = 0; kk < K; kk += 32) {
        short8 a[RT];
#pragma unroll
        for (int rt = 0; rt < RT; ++rt)
            a[rt] = APOLY ? ld8(A, (size_t)am[rt] * K + kk + quad * 8, md)
                          : *(const short8*)((const unsigned short*)A + (size_t)am[rt] * K + kk + quad * 8);
        short8 b[NT];
#pragma unroll
        for (int t = 0; t < NT; ++t)
            b[t] = *(const short8*)(sB + (t * 16 + l15) * KP + kk + quad * 8);
#pragma unroll
        for (int rt = 0; rt < RT; ++rt)
#pragma unroll
            for (int t = 0; t < NT; ++t)
                acc[rt][t] = __builtin_amdgcn_mfma_f32_16x16x32_bf16(a[rt], b[t], acc[rt][t], 0, 0, 0);
    }

    const unsigned short* Ares = (const unsigned short*)A;
    // C/D layout: col = lane&15, row = quad*4 + reg  [m89-verified]
#pragma unroll
    for (int rt = 0; rt < RT; ++rt) {
#pragma unroll
        for (int reg = 0; reg < 4; ++reg) {
            int rr = row0 + rt * 16 + quad * 4 + reg;
            if (EPI == 4) {
                int rrc = rr < M ? rr : M - 1;
                float dv = dinv[rrc];
                float val[NT];
#pragma unroll
                for (int t = 0; t < NT; ++t) {
                    int col = t * 16 + l15;
                    float z = acc[rt][t][reg]
                            + bf2f(agg[(size_t)rrc * NC + col])
                            + dv * bf2f(xw[(size_t)rrc * NC + col])
                            + ldf(bias, col, md);
                    val[t] = bf2f(Ares[(size_t)rrc * K + col]) + EPS_C * tanhf(z);
                }
                float m = val[0];
#pragma unroll
                for (int t = 1; t < NT; ++t) m = fmaxf(m, val[t]);
#pragma unroll
                for (int msk = 1; msk < 16; msk <<= 1) m = fmaxf(m, __shfl_xor(m, msk));
                float s = 0.f;
#pragma unroll
                for (int t = 0; t < NT; ++t) s += expf(val[t] - m);
#pragma unroll
                for (int msk = 1; msk < 16; msk <<= 1) s += __shfl_xor(s, msk);
                float ls = m + logf(s);
                if (rr < M) {
#pragma unroll
                    for (int t = 0; t < NT; ++t) {
                        int col = t * 16 + l15;
                        float r = val[t] - ls;
                        if (md) ((float*)opout)[(size_t)rr * NC + col] = r;
                        else    ((unsigned short*)opout)[(size_t)rr * NC + col] = f2bf(r);
                    }
                }
            } else {
                if (rr >= M) continue;
#pragma unroll
                for (int t = 0; t < NT; ++t) {
                    int col = t * 16 + l15;
                    float v = acc[rt][t][reg];
                    if (EPI == 0) { v += ldf(bias, col, md); v = v > 0.f ? v : 0.f; }
                    else if (EPI == 2) { v += ldf(bias, col, md); }
                    else if (EPI == 5) { v *= dinv[rr]; }
                    else if (EPI == 3) {
                        float dv = dinv[rr];
                        float z = v + bf2f(agg[(size_t)rr * NC + col])
                                + dv * bf2f(xw[(size_t)rr * NC + col])
                                + ldf(bias, col, md);
                        v = bf2f(Ares[(size_t)rr * K + col]) + EPS_C * tanhf(z);
                    }
                    Cout[(size_t)rr * NC + col] = f2bf(v);
                }
            }
        }
    }
}

// ---------------------------------------------------------------- fused lin2+phi2
__global__ __launch_bounds__(256) void k_lin2phi2(
    const unsigned short* __restrict__ A, const void* __restrict__ B1,
    const void* __restrict__ bias, const void* __restrict__ B2,
    unsigned short* __restrict__ h3, unsigned short* __restrict__ xws2,
    const float* __restrict__ dinv, const int* __restrict__ dmode, int M)
{
    constexpr int K1 = 128, KP1 = 136, KP2 = 40;
    __shared__ __align__(16) unsigned short sB1[32 * KP1];
    __shared__ __align__(16) unsigned short sB2[32 * KP2];
    __shared__ __align__(16) unsigned short sT[256 * KP2];
    const int md = dmode[0];

    for (int base = threadIdx.x * 8; base < 32 * K1; base += 2048) {
        int r = base / K1, c = base - r * K1;
        if (md) {
            const float* q = (const float*)B1 + base;
#pragma unroll
            for (int j = 0; j < 8; ++j) sB1[r * KP1 + c + j] = f2bf(q[j]);
        } else {
            *(short8*)(sB1 + r * KP1 + c) = *(const short8*)((const unsigned short*)B1 + base);
        }
    }
    for (int base = threadIdx.x * 8; base < 32 * 32; base += 2048) {
        int r = base / 32, c = base - r * 32;
        if (md) {
            const float* q = (const float*)B2 + base;
#pragma unroll
            for (int j = 0; j < 8; ++j) sB2[r * KP2 + c + j] = f2bf(q[j]);
        } else {
            *(short8*)(sB2 + r * KP2 + c) = *(const short8*)((const unsigned short*)B2 + base);
        }
    }
    __syncthreads();

    const int lane = threadIdx.x & 63;
    const int wave = threadIdx.x >> 6;
    const int l15  = lane & 15;
    const int quad = lane >> 4;
    const int row0 = blockIdx.x * 256 + wave * 64;

    int am[4];
#pragma unroll
    for (int rt = 0; rt < 4; ++rt) {
        int r = row0 + rt * 16 + l15;
        am[rt] = r < M ? r : M - 1;
    }

    floatx4 acc[4][2];
#pragma unroll
    for (int rt = 0; rt < 4; ++rt) { acc[rt][0] = (floatx4){0,0,0,0}; acc[rt][1] = (floatx4){0,0,0,0}; }

#pragma unroll
    for (int kk = 0; kk < K1; kk += 32) {
#pragma unroll
        for (int rt = 0; rt < 4; ++rt) {
            short8 a = *(const short8*)(A + (size_t)am[rt] * K1 + kk + quad * 8);
#pragma unroll
            for (int t = 0; t < 2; ++t) {
                short8 b = *(const short8*)(sB1 + (t * 16 + l15) * KP1 + kk + quad * 8);
                acc[rt][t] = __builtin_amdgcn_mfma_f32_16x16x32_bf16(a, b, acc[rt][t], 0, 0, 0);
            }
        }
    }
#pragma unroll
    for (int rt = 0; rt < 4; ++rt)
#pragma unroll
        for (int reg = 0; reg < 4; ++reg) {
            int rr = row0 + rt * 16 + quad * 4 + reg;
            int lr = wave * 64 + rt * 16 + quad * 4 + reg;
#pragma unroll
            for (int t = 0; t < 2; ++t) {
                int col = t * 16 + l15;
                unsigned short hv = f2bf(acc[rt][t][reg] + ldf(bias, col, md));
                sT[lr * KP2 + col] = hv;
                if (rr < M) h3[(size_t)rr * 32 + col] = hv;
            }
        }
    __syncthreads();

    floatx4 a2[4][2];
#pragma unroll
    for (int rt = 0; rt < 4; ++rt) {
        short8 a = *(const short8*)(sT + (wave * 64 + rt * 16 + l15) * KP2 + quad * 8);
#pragma unroll
        for (int t = 0; t < 2; ++t) {
            short8 b = *(const short8*)(sB2 + (t * 16 + l15) * KP2 + quad * 8);
            a2[rt][t] = __builtin_amdgcn_mfma_f32_16x16x32_bf16(a, b, (floatx4){0,0,0,0}, 0, 0, 0);
        }
    }
#pragma unroll
    for (int rt = 0; rt < 4; ++rt)
#pragma unroll
        for (int reg = 0; reg < 4; ++reg) {
            int rr = row0 + rt * 16 + quad * 4 + reg;
            if (rr >= M) continue;
            float dv = dinv[rr];
#pragma unroll
            for (int t = 0; t < 2; ++t)
                xws2[(size_t)rr * 32 + t * 16 + l15] = f2bf(dv * a2[rt][t][reg]);
        }
}

// ---------------------------------------------------------------- gather
// agg[i] = dinv[i] * sum_{j in in(i)} xws[src_j]   (xws pre-scaled by dinv[src])
template<int D, int LPN>
__global__ __launch_bounds__(256) void k_gather(
    const int* __restrict__ srt, const int* __restrict__ rs,
    const int* __restrict__ cend,
    const unsigned short* __restrict__ xws, const float* __restrict__ dinv,
    unsigned short* __restrict__ agg, int n)
{
    constexpr int NPB = 256 / LPN;
    int node = blockIdx.x * NPB + threadIdx.x / LPN;
    int l = threadIdx.x % LPN;
    if (node >= n) return;
    int j = rs[node], end = cend[node];
    float a0 = 0.f, a1 = 0.f;
    for (; j + 1 < end; j += 2) {
        int s0 = srt[j], s1 = srt[j + 1];
        unsigned int p0 = *(const unsigned int*)(xws + (size_t)s0 * D + l * 2);
        unsigned int p1 = *(const unsigned int*)(xws + (size_t)s1 * D + l * 2);
        a0 += bf2f((unsigned short)(p0 & 0xFFFFu)) + bf2f((unsigned short)(p1 & 0xFFFFu));
        a1 += bf2f((unsigned short)(p0 >> 16))     + bf2f((unsigned short)(p1 >> 16));
    }
    if (j < end) {
        int s0 = srt[j];
        unsigned int p0 = *(const unsigned int*)(xws + (size_t)s0 * D + l * 2);
        a0 += bf2f((unsigned short)(p0 & 0xFFFFu));
        a1 += bf2f((unsigned short)(p0 >> 16));
    }
    float dn = dinv[node];
    unsigned int out = (unsigned int)f2bf(dn * a0) | ((unsigned int)f2bf(dn * a1) << 16);
    *(unsigned int*)(agg + (size_t)node * D + l * 2) = out;
}

// ---------------------------------------------------------------- launch
extern "C" void kernel_launch(void* const* d_in, const int* in_sizes, int n_in,
                              void* d_out, int out_size, void* d_ws, size_t ws_size,
                              hipStream_t stream)
{
    const void* x      = d_in[0];
    const void* lin1_w = d_in[1];
    const void* lin1_b = d_in[2];
    const void* lin2_w = d_in[3];
    const void* lin2_b = d_in[4];
    const void* W1     = d_in[5];
    const void* phi1w  = d_in[6];
    const void* b1     = d_in[7];
    const void* W2     = d_in[8];
    const void* phi2w  = d_in[9];
    const void* b2     = d_in[10];
    const int* eidx    = (const int*)d_in[11];
    const int* erow = eidx;
    const int* ecol = eidx + NEDGES;

    // Workspace (high-water ~87.3 MB; ws_size >= ~129MB per R2):
    char* ws = (char*)d_ws;
    float* dinv          = (float*)ws;                    // [N] f32
    int*   dmode         = (int*)(ws + 400000);
    unsigned short* aw1  = (unsigned short*)(ws + 401408);
    unsigned short* aw2  = (unsigned short*)(ws + 435200);
    int* tot             = (int*)(ws + 440320);           // [782]
    int* bbase           = (int*)(ws + 443648);           // [782]
    int* row_start       = (int*)(ws + 446976);           // [N]
    int* cend            = (int*)(ws + 846976);           // [N]
    int* srt             = (int*)(ws + 1246976);          // [E] 6.4MB -> 7646976
    int* hist            = (int*)(ws + 7646976);          // [NCH*NBK] 1.22MB -> 8870024
    int* offb            = (int*)(ws + 8870912);          // [NCH*NBK] 1.22MB -> 10093960
    unsigned short* h1   = (unsigned short*)(ws + 10485760);          // [N,128]
    unsigned short* xws1 = h1 + (size_t)N_NODES * HID;                // [N,128]
    unsigned short* agg1 = xws1 + (size_t)N_NODES * HID;              // [N,128]
    unsigned short* h2   = xws1;   // EPI3 in-place (read-before-write per thread)
    unsigned short* h3   = h1;     // h1 dead after EPI3
    unsigned short* xws2 = agg1;   // agg1 dead after EPI3
    unsigned short* agg2 = agg1 + (size_t)N_NODES * NCLS;
    // pairs aliases h1+xws1 region start? No — pairs consumed by k_build before
    // h1 written (stream-ordered); place pairs inside agg1 region (6.4MB < 25.6MB)
    unsigned int* pairs  = (unsigned int*)agg1;

    const int GB = 256;
    const int NBLK = (N_NODES + 255) / 256;
    k_detect<<<1, 256, 0, stream>>>((const unsigned short*)x, dmode);

    // CSR build v3: radix partition, zero global atomics
    k_hist2<<<NCH, 256, 0, stream>>>(ecol, hist, NEDGES);
    k_tot<<<NBK, 256, 0, stream>>>(hist, tot);
    k_bscan<<<1, 1024, 0, stream>>>(tot, bbase);
    k_colscan<<<NBK, 512, 0, stream>>>(hist, bbase, offb);
    k_pass3<<<NCH, 256, 0, stream>>>(erow, ecol, offb, pairs, NEDGES);
    k_build<<<NBK, 256, 0, stream>>>(tot, bbase, pairs, srt, row_start, cend, dinv, N_NODES);

    // antisymmetric weights
    k_aw<<<(HID * HID + GB - 1) / GB, GB, 0, stream>>>(W1, aw1, dmode, HID);
    k_aw<<<(NCLS * NCLS + GB - 1) / GB, GB, 0, stream>>>(W2, aw2, dmode, NCLS);

    // h1 = relu(x @ lin1_w.T + lin1_b)
    k_gemm2<256, 128, 0, true, true><<<NBLK, 256, 0, stream>>>(
        x, lin1_w, lin1_b, h1, nullptr, nullptr, nullptr, dmode, nullptr, N_NODES);
    // xws1 = dinv * (h1 @ phi1_w.T)
    k_gemm2<128, 128, 5, false, true><<<NBLK, 256, 0, stream>>>(
        h1, phi1w, nullptr, xws1, nullptr, nullptr, dinv, dmode, nullptr, N_NODES);
    // agg1 = dinv * gather(xws1)
    k_gather<128, 64><<<(N_NODES + 3) / 4, 256, 0, stream>>>(
        srt, row_start, cend, xws1, dinv, agg1, N_NODES);
    // h2 = h1 + EPS*tanh(h1@aw1.T + agg1 + dinv*xws1 + b1)   (in-place on xws1)
    k_gemm2<128, 128, 3, false, false><<<NBLK, 256, 0, stream>>>(
        h1, aw1, b1, h2, agg1, xws1, dinv, dmode, nullptr, N_NODES);
    // h3 = h2@lin2_w.T + lin2_b ; xws2 = dinv*(h3@phi2_w.T)   (fused)
    k_lin2phi2<<<NBLK, 256, 0, stream>>>(h2, lin2_w, lin2_b, phi2w, h3, xws2, dinv, dmode, N_NODES);
    // agg2 = dinv * gather(xws2)
    k_gather<32, 16><<<(N_NODES + 15) / 16, 256, 0, stream>>>(
        srt, row_start, cend, xws2, dinv, agg2, N_NODES);
    // out = log_softmax(h3 + EPS*tanh(h3@aw2.T + agg2 + dinv*xws2 + b2))  (fused)
    k_gemm2<32, 32, 4, false, false><<<NBLK, 256, 0, stream>>>(
        h3, aw2, b2, nullptr, agg2, xws2, dinv, dmode, d_out, N_NODES);
}

// Round 7
// 529.351 us; speedup vs baseline: 1.7744x; 1.1542x over previous
//
#include <hip/hip_runtime.h>
#include <hip/hip_bf16.h>
#include <math.h>

// Problem constants (from reference)
#define N_NODES 100000
#define F_IN    256
#define HID     128
#define NCLS    32
#define NEDGES  1600000
#define EPS_C   0.1f
#define GAMMA_C 0.1f

// CSR build: radix partition into 782 buckets of 128 nodes, no global atomics
#define NBK   782                  // ceil(100000/128)
#define CHUNK 4096
#define NCH   391                  // ceil(1600000/4096)
#define BMAX  4096                 // bucket cap for k_build LDS (mean 2046, +45 sigma)

typedef __attribute__((ext_vector_type(8))) short short8;   // 8 bf16 = 4 VGPRs (MFMA A/B frag)
typedef __attribute__((ext_vector_type(4))) float floatx4;  // MFMA C/D frag

__device__ __forceinline__ float bf2f(unsigned short u) {
    union { unsigned int u; float f; } c;
    c.u = ((unsigned int)u) << 16;
    return c.f;
}
__device__ __forceinline__ unsigned short f2bf(float f) {
    union { float f; unsigned int u; } c; c.f = f;
    unsigned int u = c.u;
    u += 0x7FFFu + ((u >> 16) & 1u);   // round-to-nearest-even
    return (unsigned short)(u >> 16);
}

// Polymorphic scalar load: md=1 -> buffer is f32, md=0 -> bf16
__device__ __forceinline__ float ldf(const void* p, size_t i, int md) {
    return md ? ((const float*)p)[i] : bf2f(((const unsigned short*)p)[i]);
}
__device__ __forceinline__ short8 ld8(const void* p, size_t i, int md) {
    if (md) {
        const float* q = (const float*)p + i;
        short8 r;
#pragma unroll
        for (int j = 0; j < 8; ++j) r[j] = (short)f2bf(q[j]);
        return r;
    }
    return *(const short8*)((const unsigned short*)p + i);
}

// ---------------------------------------------------------------- dtype probe
__global__ void k_detect(const unsigned short* __restrict__ x, int* __restrict__ mode) {
    __shared__ int cnt;
    if (threadIdx.x == 0) cnt = 0;
    __syncthreads();
    float v = fabsf(bf2f(x[2 * threadIdx.x]));
    if (v > 1e4f || !isfinite(v)) atomicAdd(&cnt, 1);
    __syncthreads();
    if (threadIdx.x == 0) *mode = (cnt >= 8) ? 1 : 0;
}

// ---------------------------------------------------------------- CSR build v3
__global__ __launch_bounds__(256) void k_hist2(const int* __restrict__ ecol,
                                               int* __restrict__ hist, int e) {
    __shared__ int lh[NBK];
    for (int i = threadIdx.x; i < NBK; i += 256) lh[i] = 0;
    __syncthreads();
    int base = blockIdx.x * CHUNK;
    int lim = base + CHUNK; if (lim > e) lim = e;
    for (int i = base + threadIdx.x; i < lim; i += 256)
        atomicAdd(&lh[ecol[i] >> 7], 1);
    __syncthreads();
    for (int i = threadIdx.x; i < NBK; i += 256) hist[blockIdx.x * NBK + i] = lh[i];
}

__global__ __launch_bounds__(256) void k_tot(const int* __restrict__ hist, int* __restrict__ tot) {
    __shared__ int s[256];
    int b = blockIdx.x;
    int v = 0;
    for (int blk = threadIdx.x; blk < NCH; blk += 256) v += hist[blk * NBK + b];
    s[threadIdx.x] = v;
    __syncthreads();
#pragma unroll
    for (int off = 128; off > 0; off >>= 1) {
        if (threadIdx.x < off) s[threadIdx.x] += s[threadIdx.x + off];
        __syncthreads();
    }
    if (threadIdx.x == 0) tot[b] = s[0];
}

__global__ void k_bscan(const int* __restrict__ tot, int* __restrict__ bbase) {
    __shared__ int s[1024];
    int v = (threadIdx.x < NBK) ? tot[threadIdx.x] : 0;
    s[threadIdx.x] = v;
    __syncthreads();
#pragma unroll
    for (int off = 1; off < 1024; off <<= 1) {
        int t = (threadIdx.x >= off) ? s[threadIdx.x - off] : 0;
        __syncthreads();
        s[threadIdx.x] += t;
        __syncthreads();
    }
    if (threadIdx.x < NBK) bbase[threadIdx.x] = s[threadIdx.x] - v;
}

__global__ __launch_bounds__(512) void k_colscan(const int* __restrict__ hist,
                                                 const int* __restrict__ bbase,
                                                 int* __restrict__ off) {
    __shared__ int s[512];
    int b = blockIdx.x, t = threadIdx.x;
    int v = (t < NCH) ? hist[t * NBK + b] : 0;
    s[t] = v;
    __syncthreads();
#pragma unroll
    for (int o = 1; o < 512; o <<= 1) {
        int u = (t >= o) ? s[t - o] : 0;
        __syncthreads();
        s[t] += u;
        __syncthreads();
    }
    if (t < NCH) off[t * NBK + b] = s[t] - v + bbase[b];
}

__global__ __launch_bounds__(256) void k_pass3(
    const int* __restrict__ erow, const int* __restrict__ ecol,
    const int* __restrict__ off, unsigned int* __restrict__ pairs, int e)
{
    __shared__ int lh[NBK];
    __shared__ int lex[NBK + 1];
    __shared__ int cur[NBK];
    __shared__ int wsum[256];
    __shared__ unsigned int sp[CHUNK];
    int base = blockIdx.x * CHUNK;
    int lim = base + CHUNK; if (lim > e) lim = e;
    int cnt = lim - base;

    for (int i = threadIdx.x; i < NBK; i += 256) lh[i] = 0;
    __syncthreads();
    for (int i = base + threadIdx.x; i < lim; i += 256)
        atomicAdd(&lh[ecol[i] >> 7], 1);
    __syncthreads();

    int t4 = threadIdx.x * 4;
    int a0 = (t4 + 0 < NBK) ? lh[t4 + 0] : 0;
    int a1 = (t4 + 1 < NBK) ? lh[t4 + 1] : 0;
    int a2 = (t4 + 2 < NBK) ? lh[t4 + 2] : 0;
    int a3 = (t4 + 3 < NBK) ? lh[t4 + 3] : 0;
    int mysum = a0 + a1 + a2 + a3;
    wsum[threadIdx.x] = mysum;
    __syncthreads();
#pragma unroll
    for (int o = 1; o < 256; o <<= 1) {
        int u = (threadIdx.x >= o) ? wsum[threadIdx.x - o] : 0;
        __syncthreads();
        wsum[threadIdx.x] += u;
        __syncthreads();
    }
    int run = wsum[threadIdx.x] - mysum;
    if (t4 + 0 < NBK) { lex[t4 + 0] = run;            cur[t4 + 0] = run; }
    if (t4 + 1 < NBK) { lex[t4 + 1] = run + a0;       cur[t4 + 1] = run + a0; }
    if (t4 + 2 < NBK) { lex[t4 + 2] = run + a0 + a1;  cur[t4 + 2] = run + a0 + a1; }
    if (t4 + 3 < NBK) { lex[t4 + 3] = run + a0 + a1 + a2; cur[t4 + 3] = run + a0 + a1 + a2; }
    if (threadIdx.x == 0) lex[NBK] = cnt;
    __syncthreads();

    for (int i = base + threadIdx.x; i < lim; i += 256) {
        int dst = ecol[i], src = erow[i];
        int b = dst >> 7;
        int p = atomicAdd(&cur[b], 1);
        sp[p] = ((unsigned int)src << 7) | (unsigned int)(dst & 127);
    }
    __syncthreads();

    for (int i = threadIdx.x; i < cnt; i += 256) {
        int loB = 0, hiB = NBK;
        while (hiB - loB > 1) {
            int mid = (loB + hiB) >> 1;
            if (lex[mid] <= i) loB = mid; else hiB = mid;
        }
        pairs[off[blockIdx.x * NBK + loB] + (i - lex[loB])] = sp[i];
    }
}

__global__ __launch_bounds__(256) void k_build(
    const int* __restrict__ tot, const int* __restrict__ bbase,
    const unsigned int* __restrict__ pairs,
    int* __restrict__ srt, int* __restrict__ row_start, int* __restrict__ cend,
    float* __restrict__ dinv, int n)
{
    __shared__ int lh[128];
    __shared__ int lo[128];
    __shared__ unsigned int se[BMAX];
    int b = blockIdx.x;
    int nb = tot[b]; if (nb > BMAX) nb = BMAX;
    int base = bbase[b];
    if (threadIdx.x < 128) lh[threadIdx.x] = 0;
    __syncthreads();
    for (int e = threadIdx.x; e < nb; e += 256) {
        unsigned int pk = pairs[(size_t)base + e];
        se[e] = pk;
        atomicAdd(&lh[pk & 127u], 1);
    }
    __syncthreads();
    if (threadIdx.x < 128) lo[threadIdx.x] = lh[threadIdx.x];
    __syncthreads();
#pragma unroll
    for (int off = 1; off < 128; off <<= 1) {
        int t = (threadIdx.x < 128 && threadIdx.x >= off) ? lo[threadIdx.x - off] : 0;
        __syncthreads();
        if (threadIdx.x < 128) lo[threadIdx.x] += t;
        __syncthreads();
    }
    int node = b * 128 + threadIdx.x;
    if (threadIdx.x < 128 && node < n) {
        int inc = lo[threadIdx.x], cnt = lh[threadIdx.x];
        row_start[node] = base + inc - cnt;
        cend[node]      = base + inc;
        dinv[node]      = rsqrtf((float)cnt + 1.0f);
    }
    __syncthreads();
    if (threadIdx.x < 128) lh[threadIdx.x] = lo[threadIdx.x] - lh[threadIdx.x];
    __syncthreads();
    for (int e = threadIdx.x; e < nb; e += 256) {
        unsigned int pk = se[e];
        int pos = atomicAdd(&lh[pk & 127u], 1);
        srt[base + pos] = (int)(pk >> 7);
    }
}

// ---------------------------------------------------------------- weights
__global__ void k_aw(const void* __restrict__ W, unsigned short* __restrict__ aw,
                     const int* __restrict__ dmode, int d) {
    int idx = blockIdx.x * blockDim.x + threadIdx.x;
    if (idx >= d * d) return;
    int md = dmode[0];
    int n = idx / d, k = idx - n * d;
    float v = ldf(W, n * d + k, md) - ldf(W, k * d + n, md) - ((n == k) ? GAMMA_C : 0.0f);
    aw[idx] = f2bf(v);
}

// ---------------------------------------------------------------- GEMM v3
// C[M,NC] = A[M,K] @ B[NC,K]^T. B staged in padded LDS in KTILE chunks
// (LDS = NC*(KTILE+8)*2 B). 4 waves/block, RT row-tiles/wave ->
// rows/block = 64*RT. Occupancy-shaped: RT=2 + KTILE=128 gives 782 blocks,
// 34.8KB LDS (4 blocks/CU), ~64-VGPR acc.
// EPI: 0 relu(acc+bias) | 2 acc+bias | 5 dinv[r]*acc
//      3 ASC: h + EPS*tanh(acc + agg + dinv*xws + bias)          (K==NC)
//      4 ASC + fused log_softmax -> opout (poly dtype)           (K==NC==32)
template<int K, int NC, int EPI, bool APOLY, bool BPOLY, int RT, int KTILE>
__global__ __launch_bounds__(256) void k_gemm3(
    const void* A, const void* B, const void* bias,
    unsigned short* Cout,
    const unsigned short* agg, const unsigned short* xw, const float* dinv,
    const int* dmode, void* opout, int M)
{
    constexpr int KP = KTILE + 8;
    constexpr int NT = NC / 16;
    constexpr int RPB = 64 * RT;          // rows per block
    __shared__ __align__(16) unsigned short sB[NC * KP];
    const int md = dmode[0];

    const int lane = threadIdx.x & 63;
    const int wave = threadIdx.x >> 6;
    const int l15  = lane & 15;
    const int quad = lane >> 4;
    const int row0 = blockIdx.x * RPB + wave * (16 * RT);

    int am[RT];
#pragma unroll
    for (int rt = 0; rt < RT; ++rt) {
        int r = row0 + rt * 16 + l15;
        am[rt] = r < M ? r : M - 1;
    }

    floatx4 acc[RT][NT];
#pragma unroll
    for (int rt = 0; rt < RT; ++rt)
#pragma unroll
        for (int t = 0; t < NT; ++t) acc[rt][t] = (floatx4){0.f, 0.f, 0.f, 0.f};

    for (int kt = 0; kt < K; kt += KTILE) {
        // stage B[:, kt:kt+KTILE]
        if (kt > 0) __syncthreads();
        for (int base = threadIdx.x * 8; base < NC * KTILE; base += 2048) {
            int r = base / KTILE, c = base - r * KTILE;
            if (BPOLY && md) {
                const float* q = (const float*)B + (size_t)r * K + kt + c;
#pragma unroll
                for (int j = 0; j < 8; ++j) sB[r * KP + c + j] = f2bf(q[j]);
            } else {
                *(short8*)(sB + r * KP + c) =
                    *(const short8*)((const unsigned short*)B + (size_t)r * K + kt + c);
            }
        }
        __syncthreads();

#pragma unroll 2
        for (int kk = kt; kk < kt + KTILE; kk += 32) {
            short8 a[RT];
#pragma unroll
            for (int rt = 0; rt < RT; ++rt)
                a[rt] = APOLY ? ld8(A, (size_t)am[rt] * K + kk + quad * 8, md)
                              : *(const short8*)((const unsigned short*)A + (size_t)am[rt] * K + kk + quad * 8);
            short8 b[NT];
#pragma unroll
            for (int t = 0; t < NT; ++t)
                b[t] = *(const short8*)(sB + (t * 16 + l15) * KP + (kk - kt) + quad * 8);
#pragma unroll
            for (int rt = 0; rt < RT; ++rt)
#pragma unroll
                for (int t = 0; t < NT; ++t)
                    acc[rt][t] = __builtin_amdgcn_mfma_f32_16x16x32_bf16(a[rt], b[t], acc[rt][t], 0, 0, 0);
        }
    }

    const unsigned short* Ares = (const unsigned short*)A;
    // C/D layout: col = lane&15, row = quad*4 + reg  [m89-verified]
#pragma unroll
    for (int rt = 0; rt < RT; ++rt) {
#pragma unroll
        for (int reg = 0; reg < 4; ++reg) {
            int rr = row0 + rt * 16 + quad * 4 + reg;
            if (EPI == 4) {
                int rrc = rr < M ? rr : M - 1;
                float dv = dinv[rrc];
                float val[NT];
#pragma unroll
                for (int t = 0; t < NT; ++t) {
                    int col = t * 16 + l15;
                    float z = acc[rt][t][reg]
                            + bf2f(agg[(size_t)rrc * NC + col])
                            + dv * bf2f(xw[(size_t)rrc * NC + col])
                            + ldf(bias, col, md);
                    val[t] = bf2f(Ares[(size_t)rrc * K + col]) + EPS_C * tanhf(z);
                }
                float m = val[0];
#pragma unroll
                for (int t = 1; t < NT; ++t) m = fmaxf(m, val[t]);
#pragma unroll
                for (int msk = 1; msk < 16; msk <<= 1) m = fmaxf(m, __shfl_xor(m, msk));
                float s = 0.f;
#pragma unroll
                for (int t = 0; t < NT; ++t) s += expf(val[t] - m);
#pragma unroll
                for (int msk = 1; msk < 16; msk <<= 1) s += __shfl_xor(s, msk);
                float ls = m + logf(s);
                if (rr < M) {
#pragma unroll
                    for (int t = 0; t < NT; ++t) {
                        int col = t * 16 + l15;
                        float r = val[t] - ls;
                        if (md) ((float*)opout)[(size_t)rr * NC + col] = r;
                        else    ((unsigned short*)opout)[(size_t)rr * NC + col] = f2bf(r);
                    }
                }
            } else {
                if (rr >= M) continue;
#pragma unroll
                for (int t = 0; t < NT; ++t) {
                    int col = t * 16 + l15;
                    float v = acc[rt][t][reg];
                    if (EPI == 0) { v += ldf(bias, col, md); v = v > 0.f ? v : 0.f; }
                    else if (EPI == 2) { v += ldf(bias, col, md); }
                    else if (EPI == 5) { v *= dinv[rr]; }
                    else if (EPI == 3) {
                        float dv = dinv[rr];
                        float z = v + bf2f(agg[(size_t)rr * NC + col])
                                + dv * bf2f(xw[(size_t)rr * NC + col])
                                + ldf(bias, col, md);
                        v = bf2f(Ares[(size_t)rr * K + col]) + EPS_C * tanhf(z);
                    }
                    Cout[(size_t)rr * NC + col] = f2bf(v);
                }
            }
        }
    }
}

// ---------------------------------------------------------------- fused lin2+phi2
__global__ __launch_bounds__(256) void k_lin2phi2(
    const unsigned short* __restrict__ A, const void* __restrict__ B1,
    const void* __restrict__ bias, const void* __restrict__ B2,
    unsigned short* __restrict__ h3, unsigned short* __restrict__ xws2,
    const float* __restrict__ dinv, const int* __restrict__ dmode, int M)
{
    constexpr int K1 = 128, KP1 = 136, KP2 = 40;
    __shared__ __align__(16) unsigned short sB1[32 * KP1];
    __shared__ __align__(16) unsigned short sB2[32 * KP2];
    __shared__ __align__(16) unsigned short sT[256 * KP2];
    const int md = dmode[0];

    for (int base = threadIdx.x * 8; base < 32 * K1; base += 2048) {
        int r = base / K1, c = base - r * K1;
        if (md) {
            const float* q = (const float*)B1 + base;
#pragma unroll
            for (int j = 0; j < 8; ++j) sB1[r * KP1 + c + j] = f2bf(q[j]);
        } else {
            *(short8*)(sB1 + r * KP1 + c) = *(const short8*)((const unsigned short*)B1 + base);
        }
    }
    for (int base = threadIdx.x * 8; base < 32 * 32; base += 2048) {
        int r = base / 32, c = base - r * 32;
        if (md) {
            const float* q = (const float*)B2 + base;
#pragma unroll
            for (int j = 0; j < 8; ++j) sB2[r * KP2 + c + j] = f2bf(q[j]);
        } else {
            *(short8*)(sB2 + r * KP2 + c) = *(const short8*)((const unsigned short*)B2 + base);
        }
    }
    __syncthreads();

    const int lane = threadIdx.x & 63;
    const int wave = threadIdx.x >> 6;
    const int l15  = lane & 15;
    const int quad = lane >> 4;
    const int row0 = blockIdx.x * 256 + wave * 64;

    int am[4];
#pragma unroll
    for (int rt = 0; rt < 4; ++rt) {
        int r = row0 + rt * 16 + l15;
        am[rt] = r < M ? r : M - 1;
    }

    floatx4 acc[4][2];
#pragma unroll
    for (int rt = 0; rt < 4; ++rt) { acc[rt][0] = (floatx4){0,0,0,0}; acc[rt][1] = (floatx4){0,0,0,0}; }

#pragma unroll
    for (int kk = 0; kk < K1; kk += 32) {
#pragma unroll
        for (int rt = 0; rt < 4; ++rt) {
            short8 a = *(const short8*)(A + (size_t)am[rt] * K1 + kk + quad * 8);
#pragma unroll
            for (int t = 0; t < 2; ++t) {
                short8 b = *(const short8*)(sB1 + (t * 16 + l15) * KP1 + kk + quad * 8);
                acc[rt][t] = __builtin_amdgcn_mfma_f32_16x16x32_bf16(a, b, acc[rt][t], 0, 0, 0);
            }
        }
    }
#pragma unroll
    for (int rt = 0; rt < 4; ++rt)
#pragma unroll
        for (int reg = 0; reg < 4; ++reg) {
            int rr = row0 + rt * 16 + quad * 4 + reg;
            int lr = wave * 64 + rt * 16 + quad * 4 + reg;
#pragma unroll
            for (int t = 0; t < 2; ++t) {
                int col = t * 16 + l15;
                unsigned short hv = f2bf(acc[rt][t][reg] + ldf(bias, col, md));
                sT[lr * KP2 + col] = hv;
                if (rr < M) h3[(size_t)rr * 32 + col] = hv;
            }
        }
    __syncthreads();

    floatx4 a2[4][2];
#pragma unroll
    for (int rt = 0; rt < 4; ++rt) {
        short8 a = *(const short8*)(sT + (wave * 64 + rt * 16 + l15) * KP2 + quad * 8);
#pragma unroll
        for (int t = 0; t < 2; ++t) {
            short8 b = *(const short8*)(sB2 + (t * 16 + l15) * KP2 + quad * 8);
            a2[rt][t] = __builtin_amdgcn_mfma_f32_16x16x32_bf16(a, b, (floatx4){0,0,0,0}, 0, 0, 0);
        }
    }
#pragma unroll
    for (int rt = 0; rt < 4; ++rt)
#pragma unroll
        for (int reg = 0; reg < 4; ++reg) {
            int rr = row0 + rt * 16 + quad * 4 + reg;
            if (rr >= M) continue;
            float dv = dinv[rr];
#pragma unroll
            for (int t = 0; t < 2; ++t)
                xws2[(size_t)rr * 32 + t * 16 + l15] = f2bf(dv * a2[rt][t][reg]);
        }
}

// ---------------------------------------------------------------- gather
// agg[i] = dinv[i] * sum_{j in in(i)} xws[src_j]   (xws pre-scaled by dinv[src])
template<int D, int LPN>
__global__ __launch_bounds__(256) void k_gather(
    const int* __restrict__ srt, const int* __restrict__ rs,
    const int* __restrict__ cend,
    const unsigned short* __restrict__ xws, const float* __restrict__ dinv,
    unsigned short* __restrict__ agg, int n)
{
    constexpr int NPB = 256 / LPN;
    int node = blockIdx.x * NPB + threadIdx.x / LPN;
    int l = threadIdx.x % LPN;
    if (node >= n) return;
    int j = rs[node], end = cend[node];
    float a0 = 0.f, a1 = 0.f;
    for (; j + 1 < end; j += 2) {
        int s0 = srt[j], s1 = srt[j + 1];
        unsigned int p0 = *(const unsigned int*)(xws + (size_t)s0 * D + l * 2);
        unsigned int p1 = *(const unsigned int*)(xws + (size_t)s1 * D + l * 2);
        a0 += bf2f((unsigned short)(p0 & 0xFFFFu)) + bf2f((unsigned short)(p1 & 0xFFFFu));
        a1 += bf2f((unsigned short)(p0 >> 16))     + bf2f((unsigned short)(p1 >> 16));
    }
    if (j < end) {
        int s0 = srt[j];
        unsigned int p0 = *(const unsigned int*)(xws + (size_t)s0 * D + l * 2);
        a0 += bf2f((unsigned short)(p0 & 0xFFFFu));
        a1 += bf2f((unsigned short)(p0 >> 16));
    }
    float dn = dinv[node];
    unsigned int out = (unsigned int)f2bf(dn * a0) | ((unsigned int)f2bf(dn * a1) << 16);
    *(unsigned int*)(agg + (size_t)node * D + l * 2) = out;
}

// ---------------------------------------------------------------- launch
extern "C" void kernel_launch(void* const* d_in, const int* in_sizes, int n_in,
                              void* d_out, int out_size, void* d_ws, size_t ws_size,
                              hipStream_t stream)
{
    const void* x      = d_in[0];
    const void* lin1_w = d_in[1];
    const void* lin1_b = d_in[2];
    const void* lin2_w = d_in[3];
    const void* lin2_b = d_in[4];
    const void* W1     = d_in[5];
    const void* phi1w  = d_in[6];
    const void* b1     = d_in[7];
    const void* W2     = d_in[8];
    const void* phi2w  = d_in[9];
    const void* b2     = d_in[10];
    const int* eidx    = (const int*)d_in[11];
    const int* erow = eidx;
    const int* ecol = eidx + NEDGES;

    // Workspace (high-water ~87.3 MB)
    char* ws = (char*)d_ws;
    float* dinv          = (float*)ws;                    // [N] f32
    int*   dmode         = (int*)(ws + 400000);
    unsigned short* aw1  = (unsigned short*)(ws + 401408);
    unsigned short* aw2  = (unsigned short*)(ws + 435200);
    int* tot             = (int*)(ws + 440320);           // [782]
    int* bbase           = (int*)(ws + 443648);           // [782]
    int* row_start       = (int*)(ws + 446976);           // [N]
    int* cend            = (int*)(ws + 846976);           // [N]
    int* srt             = (int*)(ws + 1246976);          // [E] 6.4MB
    int* hist            = (int*)(ws + 7646976);          // [NCH*NBK]
    int* offb            = (int*)(ws + 8870912);          // [NCH*NBK]
    unsigned short* h1   = (unsigned short*)(ws + 10485760);          // [N,128]
    unsigned short* xws1 = h1 + (size_t)N_NODES * HID;                // [N,128]
    unsigned short* agg1 = xws1 + (size_t)N_NODES * HID;              // [N,128]
    unsigned short* h2   = xws1;   // EPI3 in-place (read-before-write per thread)
    unsigned short* h3   = h1;     // h1 dead after EPI3
    unsigned short* xws2 = agg1;   // agg1 dead after EPI3
    unsigned short* agg2 = agg1 + (size_t)N_NODES * NCLS;
    unsigned int* pairs  = (unsigned int*)agg1;  // consumed by k_build before agg1 written

    const int GB = 256;
    const int NB128 = (N_NODES + 127) / 128;   // 782 blocks (128 rows/block)
    k_detect<<<1, 256, 0, stream>>>((const unsigned short*)x, dmode);

    // CSR build v3: radix partition, zero global atomics
    k_hist2<<<NCH, 256, 0, stream>>>(ecol, hist, NEDGES);
    k_tot<<<NBK, 256, 0, stream>>>(hist, tot);
    k_bscan<<<1, 1024, 0, stream>>>(tot, bbase);
    k_colscan<<<NBK, 512, 0, stream>>>(hist, bbase, offb);
    k_pass3<<<NCH, 256, 0, stream>>>(erow, ecol, offb, pairs, NEDGES);
    k_build<<<NBK, 256, 0, stream>>>(tot, bbase, pairs, srt, row_start, cend, dinv, N_NODES);

    // antisymmetric weights
    k_aw<<<(HID * HID + GB - 1) / GB, GB, 0, stream>>>(W1, aw1, dmode, HID);
    k_aw<<<(NCLS * NCLS + GB - 1) / GB, GB, 0, stream>>>(W2, aw2, dmode, NCLS);

    // h1 = relu(x @ lin1_w.T + lin1_b)          RT=2, KTILE=128: 34.8KB LDS
    k_gemm3<256, 128, 0, true, true, 2, 128><<<NB128, 256, 0, stream>>>(
        x, lin1_w, lin1_b, h1, nullptr, nullptr, nullptr, dmode, nullptr, N_NODES);
    // xws1 = dinv * (h1 @ phi1_w.T)
    k_gemm3<128, 128, 5, false, true, 2, 128><<<NB128, 256, 0, stream>>>(
        h1, phi1w, nullptr, xws1, nullptr, nullptr, dinv, dmode, nullptr, N_NODES);
    // agg1 = dinv * gather(xws1)
    k_gather<128, 64><<<(N_NODES + 3) / 4, 256, 0, stream>>>(
        srt, row_start, cend, xws1, dinv, agg1, N_NODES);
    // h2 = h1 + EPS*tanh(h1@aw1.T + agg1 + dinv*xws1 + b1)   (in-place on xws1)
    k_gemm3<128, 128, 3, false, false, 2, 128><<<NB128, 256, 0, stream>>>(
        h1, aw1, b1, h2, agg1, xws1, dinv, dmode, nullptr, N_NODES);
    // h3 = h2@lin2_w.T + lin2_b ; xws2 = dinv*(h3@phi2_w.T)   (fused)
    k_lin2phi2<<<(N_NODES + 255) / 256, 256, 0, stream>>>(
        h2, lin2_w, lin2_b, phi2w, h3, xws2, dinv, dmode, N_NODES);
    // agg2 = dinv * gather(xws2)
    k_gather<32, 16><<<(N_NODES + 15) / 16, 256, 0, stream>>>(
        srt, row_start, cend, xws2, dinv, agg2, N_NODES);
    // out = log_softmax(h3 + EPS*tanh(h3@aw2.T + agg2 + dinv*xws2 + b2))  (fused)
    k_gemm3<32, 32, 4, false, false, 2, 32><<<NB128, 256, 0, stream>>>(
        h3, aw2, b2, nullptr, agg2, xws2, dinv, dmode, d_out, N_NODES);
}